// Round 4
// baseline (533.297 us; speedup 1.0000x reference)
//
#include <hip/hip_runtime.h>
#include <cstdint>
#include <cstddef>

typedef _Float16 f16x8 __attribute__((ext_vector_type(8)));
typedef _Float16 f16x4 __attribute__((ext_vector_type(4)));
typedef float f32x4 __attribute__((ext_vector_type(4)));

static __device__ __forceinline__ float elu_f(float t) {
    return t > 0.0f ? t : expm1f(t);
}

// ---------------- weight prep: fp32 [K][C_OUT] -> fp16 tiled [y][t][kc][n][8] ----------------
template<int KTOT, int C_OUT, int BN>
__global__ __launch_bounds__(256)
void prep_w(const float* __restrict__ W, _Float16* __restrict__ o)
{
    constexpr int KT = KTOT/64;
    int i = blockIdx.x * 256 + threadIdx.x;
    if (i >= KTOT*C_OUT) return;
    int j = i & 7;
    int rest = i >> 3;
    int n = rest % BN;
    int kc = (rest / BN) & 7;
    int t = (rest / (BN*8)) % KT;
    int y = rest / (BN*8*KT);
    int k = t*64 + kc*8 + j;
    o[i] = (_Float16)W[(size_t)k*C_OUT + y*BN + n];
}

// Level-0 weights: W0 is (36, 32); pad K to 64, layout k = s*4 + c (c<3 real).
__global__ __launch_bounds__(256)
void prep_w0(const float* __restrict__ W, _Float16* __restrict__ o)
{
    int i = blockIdx.x * 256 + threadIdx.x;
    if (i >= 2048) return;
    int j = i & 7;
    int n = (i >> 3) & 31;
    int kc = i >> 8;
    int k = kc*8 + j;
    int s = k >> 2, c = k & 3;
    float v = (s < 12 && c < 3) ? W[(size_t)(s*3 + c)*32 + n] : 0.0f;
    o[i] = (_Float16)v;
}

// ---------------- fused conv+pool, MFMA fp16, levels 1-3 (fp16 activations in) ----------------
template<int C_IN, int C_OUT, int P, int BN, int WGM, int WGN, bool OUT_HALF>
__global__ __launch_bounds__(256)
void conv_pool_mfma(const _Float16* __restrict__ x, const int* __restrict__ spiral,
                    const _Float16* __restrict__ Wp, const float* __restrict__ bias,
                    const int* __restrict__ didx, const float* __restrict__ dwt,
                    void* __restrict__ outv, int vshift_in, int vshift_out)
{
    constexpr int R    = 3*P;
    constexpr int KTOT = 12*C_IN;
    constexpr int KT   = KTOT/64;
    constexpr int WTM  = R/WGM;
    constexpr int WTN  = BN/WGN;
    constexpr int NMT  = WTM/16;
    constexpr int NNT  = WTN/16;
    constexpr int C4   = BN/4;
    constexpr int STAGE_B = 64*R*2 + 64*BN*2;
    constexpr int EPI_B   = R*(BN+4)*4;
    constexpr int SMEM_B  = STAGE_B > EPI_B ? STAGE_B : EPI_B;
    static_assert(WTM % 16 == 0 && WTN % 16 == 0, "tile");
    static_assert((R*8) % 256 == 0 && (P*C4) % 256 == 0, "loops");

    __shared__ char smem[SMEM_B] __attribute__((aligned(16)));
    _Float16* As = (_Float16*)smem;
    _Float16* Ws = As + 64*R;

    const int tid  = threadIdx.x;
    const int wave = tid >> 6;
    const int lane = tid & 63;
    const int quad = lane >> 4;
    const int l16  = lane & 15;
    const int wm   = wave / WGN;
    const int wn   = wave % WGN;
    const int pu0  = blockIdx.x * P;
    const int n0   = blockIdx.y * BN;
    const int vmask_out = (1 << vshift_out) - 1;

    f32x4 acc[NMT][NNT];
    #pragma unroll
    for (int i = 0; i < NMT; ++i)
        #pragma unroll
        for (int j = 0; j < NNT; ++j) acc[i][j] = (f32x4){0.f, 0.f, 0.f, 0.f};

    for (int t = 0; t < KT; ++t) {
        // ---- stage A: double-indirect gather, r-inner (conflict-free LDS writes) ----
        #pragma unroll
        for (int e = tid; e < R*8; e += 256) {
            int kc = e / R;
            int r  = e - kc*R;
            int ul = r / 3;
            int kp = r - ul*3;
            int pu = pu0 + ul;
            int b  = pu >> vshift_out;
            int u  = pu & vmask_out;
            int v  = didx[u*3 + kp];
            int k  = t*64 + kc*8;
            int s  = k / C_IN;
            int c  = k & (C_IN - 1);
            int g  = spiral[v*12 + s];
            const _Float16* src = x + ((size_t)(((size_t)b << vshift_in) + g)*C_IN + c);
            *(f16x8*)&As[(kc*R + r)*8] = *(const f16x8*)src;
        }
        // ---- stage W: flat coalesced copy of this (y, t) tile ----
        {
            const _Float16* wsrc = Wp + (size_t)(blockIdx.y*KT + t)*(64*BN);
            #pragma unroll
            for (int e = tid; e < BN*8; e += 256)
                *(f16x8*)&Ws[e*8] = *(const f16x8*)&wsrc[e*8];
        }
        __syncthreads();

        #pragma unroll
        for (int kt = 0; kt < 2; ++kt) {
            f16x8 af[NMT], bf[NNT];
            #pragma unroll
            for (int i = 0; i < NMT; ++i) {
                int m_local = wm*WTM + i*16 + l16;
                af[i] = *(const f16x8*)&As[((kt*4 + quad)*R + m_local)*8];
            }
            #pragma unroll
            for (int j = 0; j < NNT; ++j) {
                int n_local = wn*WTN + j*16 + l16;
                bf[j] = *(const f16x8*)&Ws[((kt*4 + quad)*BN + n_local)*8];
            }
            #pragma unroll
            for (int i = 0; i < NMT; ++i)
                #pragma unroll
                for (int j = 0; j < NNT; ++j)
                    acc[i][j] = __builtin_amdgcn_mfma_f32_16x16x32_f16(
                        af[i], bf[j], acc[i][j], 0, 0, 0);
        }
        __syncthreads();
    }

    // ---- epilogue: bias+ELU rows into LDS, then 3-row weighted combine ----
    float* E = (float*)smem;
    float bv[NNT];
    #pragma unroll
    for (int j = 0; j < NNT; ++j)
        bv[j] = bias[n0 + wn*WTN + j*16 + l16];

    #pragma unroll
    for (int i = 0; i < NMT; ++i) {
        int row_base = wm*WTM + i*16 + quad*4;
        #pragma unroll
        for (int j = 0; j < NNT; ++j) {
            int col = wn*WTN + j*16 + l16;
            #pragma unroll
            for (int r = 0; r < 4; ++r)
                E[(size_t)(row_base + r)*(BN+4) + col] = elu_f(acc[i][j][r] + bv[j]);
        }
    }
    __syncthreads();

    const float4* E4 = (const float4*)smem;
    #pragma unroll
    for (int e = tid; e < P*C4; e += 256) {
        int ul = e / C4;
        int c4 = e - ul*C4;
        int pu = pu0 + ul;
        int u  = pu & vmask_out;
        const float* w = dwt + u*3;
        float4 a0 = E4[(size_t)(ul*3 + 0)*(C4+1) + c4];
        float4 a1 = E4[(size_t)(ul*3 + 1)*(C4+1) + c4];
        float4 a2 = E4[(size_t)(ul*3 + 2)*(C4+1) + c4];
        float ox = w[0]*a0.x + w[1]*a1.x + w[2]*a2.x;
        float oy = w[0]*a0.y + w[1]*a1.y + w[2]*a2.y;
        float oz = w[0]*a0.z + w[1]*a1.z + w[2]*a2.z;
        float ow = w[0]*a0.w + w[1]*a1.w + w[2]*a2.w;
        if (OUT_HALF) {
            f16x4 h; h[0]=(_Float16)ox; h[1]=(_Float16)oy; h[2]=(_Float16)oz; h[3]=(_Float16)ow;
            *(f16x4*)&((_Float16*)outv)[(size_t)pu*C_OUT + n0 + c4*4] = h;
        } else {
            float4 o; o.x=ox; o.y=oy; o.z=oz; o.w=ow;
            *(float4*)&((float*)outv)[(size_t)pu*C_OUT + n0 + c4*4] = o;
        }
    }
}

// ---------------- fused conv0+pool0 (fp32 x in, C_IN=3 padded to 4, K=36->64) ----------------
__global__ __launch_bounds__(256)
void conv0_pool_mfma(const float* __restrict__ x, const int* __restrict__ spiral,
                     const _Float16* __restrict__ Wp, const float* __restrict__ bias,
                     const int* __restrict__ didx, const float* __restrict__ dwt,
                     _Float16* __restrict__ out)
{
    constexpr int P = 128, R = 384, BN = 32;
    constexpr int NMT = 6, NNT = 2;
    constexpr int C4 = BN/4;
    constexpr int STAGE_B = 64*R*2 + 64*BN*2;
    constexpr int EPI_B   = R*(BN+4)*4;
    constexpr int SMEM_B  = STAGE_B > EPI_B ? STAGE_B : EPI_B;
    __shared__ char smem[SMEM_B] __attribute__((aligned(16)));
    _Float16* As = (_Float16*)smem;
    _Float16* Ws = As + 64*R;

    const int tid  = threadIdx.x;
    const int wave = tid >> 6;
    const int lane = tid & 63;
    const int quad = lane >> 4;
    const int l16  = lane & 15;
    const int pu0  = blockIdx.x * P;

    f32x4 acc[NMT][NNT];
    #pragma unroll
    for (int i = 0; i < NMT; ++i)
        #pragma unroll
        for (int j = 0; j < NNT; ++j) acc[i][j] = (f32x4){0.f, 0.f, 0.f, 0.f};

    // stage A, r-inner: chunks kc 0..5 = spiral pairs (3 reals + pad), 6..7 zero
    #pragma unroll
    for (int e = tid; e < R*8; e += 256) {
        int kc = e / R;
        int r  = e - kc*R;
        f16x8 h = (f16x8){0,0,0,0,0,0,0,0};
        if (kc < 6) {
            int ul = r / 3;
            int kp = r - ul*3;
            int pu = pu0 + ul;
            int b  = pu >> 13;
            int u  = pu & 8191;
            int v  = didx[u*3 + kp];
            int g0 = spiral[v*12 + kc*2];
            int g1 = spiral[v*12 + kc*2 + 1];
            const float* q0 = x + (size_t)(((size_t)b << 15) + g0)*3;
            const float* q1 = x + (size_t)(((size_t)b << 15) + g1)*3;
            h[0] = (_Float16)q0[0]; h[1] = (_Float16)q0[1]; h[2] = (_Float16)q0[2];
            h[4] = (_Float16)q1[0]; h[5] = (_Float16)q1[1]; h[6] = (_Float16)q1[2];
        }
        *(f16x8*)&As[(kc*R + r)*8] = h;
    }
    if (tid < 256) {
        *(f16x8*)&Ws[tid*8] = *(const f16x8*)&Wp[tid*8];
    }
    __syncthreads();

    #pragma unroll
    for (int kt = 0; kt < 2; ++kt) {
        f16x8 af[NMT], bf[NNT];
        #pragma unroll
        for (int i = 0; i < NMT; ++i) {
            int m_local = wave*96 + i*16 + l16;
            af[i] = *(const f16x8*)&As[((kt*4 + quad)*R + m_local)*8];
        }
        #pragma unroll
        for (int j = 0; j < NNT; ++j) {
            int n_local = j*16 + l16;
            bf[j] = *(const f16x8*)&Ws[((kt*4 + quad)*BN + n_local)*8];
        }
        #pragma unroll
        for (int i = 0; i < NMT; ++i)
            #pragma unroll
            for (int j = 0; j < NNT; ++j)
                acc[i][j] = __builtin_amdgcn_mfma_f32_16x16x32_f16(
                    af[i], bf[j], acc[i][j], 0, 0, 0);
    }
    __syncthreads();

    float* E = (float*)smem;
    float bv[NNT];
    #pragma unroll
    for (int j = 0; j < NNT; ++j) bv[j] = bias[j*16 + l16];

    #pragma unroll
    for (int i = 0; i < NMT; ++i) {
        int row_base = wave*96 + i*16 + quad*4;
        #pragma unroll
        for (int j = 0; j < NNT; ++j) {
            int col = j*16 + l16;
            #pragma unroll
            for (int r = 0; r < 4; ++r)
                E[(size_t)(row_base + r)*(BN+4) + col] = elu_f(acc[i][j][r] + bv[j]);
        }
    }
    __syncthreads();

    const float4* E4 = (const float4*)smem;
    #pragma unroll
    for (int e = tid; e < P*C4; e += 256) {
        int ul = e / C4;
        int c4 = e - ul*C4;
        int pu = pu0 + ul;
        int u  = pu & 8191;
        const float* w = dwt + u*3;
        float4 a0 = E4[(size_t)(ul*3 + 0)*(C4+1) + c4];
        float4 a1 = E4[(size_t)(ul*3 + 1)*(C4+1) + c4];
        float4 a2 = E4[(size_t)(ul*3 + 2)*(C4+1) + c4];
        f16x4 h;
        h[0] = (_Float16)(w[0]*a0.x + w[1]*a1.x + w[2]*a2.x);
        h[1] = (_Float16)(w[0]*a0.y + w[1]*a1.y + w[2]*a2.y);
        h[2] = (_Float16)(w[0]*a0.z + w[1]*a1.z + w[2]*a2.z);
        h[3] = (_Float16)(w[0]*a0.w + w[1]*a1.w + w[2]*a2.w);
        *(f16x4*)&out[(size_t)pu*BN + c4*4] = h;
    }
}

// ---------------- FC1: M=32, K=32768, N=512, memory-bound on Wl1 ----------------
// 256 blocks, each a k-chunk of 128. Thread = (mh, q): 16 m-rows x 4 n-cols.
__global__ __launch_bounds__(256)
void fc1_partial(const float* __restrict__ xflat, const float* __restrict__ Wl1,
                 float* __restrict__ acc_out)
{
    __shared__ float xs[32][128];
    const int tid = threadIdx.x;
    const int q  = tid & 127;
    const int mh = tid >> 7;
    const int kbase = blockIdx.x * 128;

    for (int e = tid; e < 32*32; e += 256) {
        int m = e >> 5, k4 = e & 31;
        *(float4*)&xs[m][k4*4] = *(const float4*)&xflat[(size_t)m*32768 + kbase + k4*4];
    }
    __syncthreads();

    float acc[16][4];
    #pragma unroll
    for (int m = 0; m < 16; ++m)
        #pragma unroll
        for (int j = 0; j < 4; ++j) acc[m][j] = 0.0f;

    const float* Wb = Wl1 + (size_t)kbase*512 + q*4;
    for (int k = 0; k < 128; k += 4) {
        float4 w0 = *(const float4*)(Wb + (size_t)(k+0)*512);
        float4 w1 = *(const float4*)(Wb + (size_t)(k+1)*512);
        float4 w2 = *(const float4*)(Wb + (size_t)(k+2)*512);
        float4 w3 = *(const float4*)(Wb + (size_t)(k+3)*512);
        #pragma unroll
        for (int m = 0; m < 16; ++m) {
            float4 xv = *(const float4*)&xs[mh*16 + m][k];
            acc[m][0] += xv.x*w0.x + xv.y*w1.x + xv.z*w2.x + xv.w*w3.x;
            acc[m][1] += xv.x*w0.y + xv.y*w1.y + xv.z*w2.y + xv.w*w3.y;
            acc[m][2] += xv.x*w0.z + xv.y*w1.z + xv.z*w2.z + xv.w*w3.z;
            acc[m][3] += xv.x*w0.w + xv.y*w1.w + xv.z*w2.w + xv.w*w3.w;
        }
    }
    #pragma unroll
    for (int m = 0; m < 16; ++m)
        #pragma unroll
        for (int j = 0; j < 4; ++j)
            atomicAdd(&acc_out[(size_t)(mh*16 + m)*512 + q*4 + j], acc[m][j]);
}

__global__ __launch_bounds__(256)
void fc1_finish(const float* __restrict__ acc, const float* __restrict__ bl1,
                float* __restrict__ hout)
{
    int i = blockIdx.x * blockDim.x + threadIdx.x;
    float t = acc[i] + bl1[i & 511];
    hout[i] = elu_f(t);
}

__global__ __launch_bounds__(64)
void fc2_kernel(const float* __restrict__ h, const float* __restrict__ Wl2,
                const float* __restrict__ bl2, float* __restrict__ y)
{
    int m = blockIdx.x;
    int n = threadIdx.x;
    float s = bl2[n];
    for (int k = 0; k < 512; ++k)
        s += h[(size_t)m*512 + k] * Wl2[(size_t)k*64 + n];
    y[(size_t)m*64 + n] = s;
}

extern "C" void kernel_launch(void* const* d_in, const int* in_sizes, int n_in,
                              void* d_out, int out_size, void* d_ws, size_t ws_size,
                              hipStream_t stream)
{
    (void)in_sizes; (void)n_in; (void)out_size;

    const float* x0 = (const float*)d_in[0];
    const int*   sp[4]; const int* didx[4]; const float* dwp[4];
    const float* Wp[4]; const float* bp[4];
    for (int i = 0; i < 4; ++i) {
        sp[i]   = (const int*)  d_in[1 + i*5 + 0];
        didx[i] = (const int*)  d_in[1 + i*5 + 1];
        dwp[i]  = (const float*)d_in[1 + i*5 + 2];
        Wp[i]   = (const float*)d_in[1 + i*5 + 3];
        bp[i]   = (const float*)d_in[1 + i*5 + 4];
    }
    const float* Wl1 = (const float*)d_in[21];
    const float* bl1 = (const float*)d_in[22];
    const float* Wl2 = (const float*)d_in[23];
    const float* bl2 = (const float*)d_in[24];
    float* out = (float*)d_out;

    char* wsb = (char*)d_ws;
    float* persist  = (float*)wsb;                        // 4 MB: (32,128,256) fp32
    float* fc1_acc  = (float*)(wsb + 4194304);            // 64 KB
    _Float16* w0h   = (_Float16*)(wsb + 4194304 + 65536); //   2,048 halfs
    _Float16* w1h   = w0h + 2048;                         //  24,576 halfs
    _Float16* w2h   = w1h + 24576;                        //  98,304 halfs
    _Float16* w3h   = w2h + 98304;                        // 393,216 halfs
    char* bufs      = wsb + 5296128;

    // per-batch-unit pooled fp16 buffers: 512K + 256K + 128K = 896 KB
    int Bc = 32;
    while (Bc > 1 && (size_t)5296128 + (size_t)Bc*917504ULL > ws_size)
        Bc >>= 1;
    _Float16* pooled0 = (_Float16*)bufs;
    _Float16* pooled1 = pooled0 + (size_t)Bc*262144ULL;
    _Float16* pooled2 = pooled1 + (size_t)Bc*131072ULL;

    prep_w0<<<8, 256, 0, stream>>>(Wp[0], w0h);
    prep_w< 384,  64,  64><<<( 24576 + 255)/256, 256, 0, stream>>>(Wp[1], w1h);
    prep_w< 768, 128, 128><<<( 98304 + 255)/256, 256, 0, stream>>>(Wp[2], w2h);
    prep_w<1536, 256, 128><<<(393216 + 255)/256, 256, 0, stream>>>(Wp[3], w3h);

    hipMemsetAsync(fc1_acc, 0, 16384*sizeof(float), stream);

    for (int b0 = 0; b0 < 32; b0 += Bc) {
        const float* xin = x0 + (size_t)b0*32768*3;

        // L0: conv(3->32) + pool -> fp16 (Bc, 8192, 32)
        conv0_pool_mfma<<<Bc*8192/128, 256, 0, stream>>>(
            xin, sp[0], w0h, bp[0], didx[0], dwp[0], pooled0);

        // L1: conv(32->64, K=384) + pool -> fp16 (Bc, 2048, 64)
        conv_pool_mfma<32,64,64,64,4,1,true><<<Bc*2048/64, 256, 0, stream>>>(
            pooled0, sp[1], w1h, bp[1], didx[1], dwp[1], pooled1, 13, 11);

        // L2: conv(64->128, K=768) + pool -> fp16 (Bc, 512, 128)
        conv_pool_mfma<64,128,32,128,2,2,true><<<Bc*512/32, 256, 0, stream>>>(
            pooled1, sp[2], w2h, bp[2], didx[2], dwp[2], pooled2, 11, 9);

        // L3: conv(128->256, K=1536) + pool -> fp32 persist chunk (Bc, 128, 256)
        conv_pool_mfma<128,256,32,128,2,2,false><<<dim3(Bc*128/32, 2), 256, 0, stream>>>(
            pooled2, sp[3], w3h, bp[3], didx[3], dwp[3],
            persist + (size_t)b0*32768, 9, 7);
    }

    // FC1: (32, 32768) @ (32768, 512) + bias, ELU -> d_out[0:16384]
    fc1_partial<<<256, 256, 0, stream>>>(persist, Wl1, fc1_acc);
    fc1_finish<<<64, 256, 0, stream>>>(fc1_acc, bl1, out);

    // FC2: (32, 512) @ (512, 64) + bias -> d_out[16384:18432]
    fc2_kernel<<<32, 64, 0, stream>>>(out, Wl2, bl2, out + 16384);
}

// Round 5
// 394.958 us; speedup vs baseline: 1.3503x; 1.3503x over previous
//
#include <hip/hip_runtime.h>
#include <cstdint>
#include <cstddef>

typedef _Float16 f16x8 __attribute__((ext_vector_type(8)));
typedef _Float16 f16x4 __attribute__((ext_vector_type(4)));
typedef float f32x4 __attribute__((ext_vector_type(4)));

static __device__ __forceinline__ float elu_f(float t) {
    return t > 0.0f ? t : expm1f(t);
}

// ---------------- x prep: fp32 (B,V,3) -> fp16 (B,V,4) zero-padded ----------------
__global__ __launch_bounds__(256)
void prep_x(const float* __restrict__ x, _Float16* __restrict__ xh4, int total)
{
    int i = blockIdx.x * 256 + threadIdx.x;
    if (i >= total) return;
    const float* p = x + (size_t)i*3;
    f16x4 h;
    h[0] = (_Float16)p[0]; h[1] = (_Float16)p[1]; h[2] = (_Float16)p[2]; h[3] = (_Float16)0.f;
    *(f16x4*)&xh4[(size_t)i*4] = h;
}

// ---------------- weight prep: fp32 [K][C_OUT] -> fp16 tiled [y][t][kc][n][8] ----------------
template<int KTOT, int C_OUT, int BN>
__global__ __launch_bounds__(256)
void prep_w(const float* __restrict__ W, _Float16* __restrict__ o)
{
    constexpr int KT = KTOT/64;
    int i = blockIdx.x * 256 + threadIdx.x;
    if (i >= KTOT*C_OUT) return;
    int j = i & 7;
    int rest = i >> 3;
    int n = rest % BN;
    int kc = (rest / BN) & 7;
    int t = (rest / (BN*8)) % KT;
    int y = rest / (BN*8*KT);
    int k = t*64 + kc*8 + j;
    o[i] = (_Float16)W[(size_t)k*C_OUT + y*BN + n];
}

// Level-0 weights: (36,32) -> padded K=64, k = s*4 + c layout, tile [kc][n][8]
__global__ __launch_bounds__(256)
void prep_w0(const float* __restrict__ W, _Float16* __restrict__ o)
{
    int i = blockIdx.x * 256 + threadIdx.x;
    if (i >= 2048) return;
    int j = i & 7;
    int n = (i >> 3) & 31;
    int kc = i >> 8;
    int k = kc*8 + j;
    int s = k >> 2, c = k & 3;
    float v = (s < 12 && c < 3) ? W[(size_t)(s*3 + c)*32 + n] : 0.0f;
    o[i] = (_Float16)v;
}

// ---------------- fused conv+pool, MFMA fp16, levels 1-3 ----------------
// As layout [r][9 chunks][8 halfs] (pad chunk -> 2-way-max LDS conflicts).
// gidx[r][12] = flat vertex index (batch pre-added), computed once per block.
// Staging is kc-inner: a wave reads 8 rows x 8 chunks; per row the 64-k tile
// is contiguous (C_IN>=64: one 128B block; C_IN=32: two 64B blocks).
template<int C_IN, int C_OUT, int P, int BN, int WGM, int WGN, bool OUT_HALF>
__global__ __launch_bounds__(256)
void conv_pool_mfma(const _Float16* __restrict__ x, const int* __restrict__ spiral,
                    const _Float16* __restrict__ Wp, const float* __restrict__ bias,
                    const int* __restrict__ didx, const float* __restrict__ dwt,
                    void* __restrict__ outv, int vshift_in, int vshift_out)
{
    constexpr int R    = 3*P;
    constexpr int KTOT = 12*C_IN;
    constexpr int KT   = KTOT/64;
    constexpr int WTM  = R/WGM;
    constexpr int WTN  = BN/WGN;
    constexpr int NMT  = WTM/16;
    constexpr int NNT  = WTN/16;
    constexpr int C4   = BN/4;
    constexpr int AS_B = R*9*8*2;
    constexpr int WS_B = 64*BN*2;
    constexpr int GI_B = R*12*4;
    constexpr int STAGE_B = AS_B + WS_B + GI_B;
    constexpr int EPI_B   = R*(BN+4)*4;
    constexpr int SMEM_B  = STAGE_B > EPI_B ? STAGE_B : EPI_B;
    static_assert(WTM % 16 == 0 && WTN % 16 == 0, "tile");
    static_assert((R*8) % 256 == 0 && (P*C4) % 256 == 0, "loops");

    __shared__ char smem[SMEM_B] __attribute__((aligned(16)));
    _Float16* As = (_Float16*)smem;
    _Float16* Ws = (_Float16*)(smem + AS_B);
    int* gidx    = (int*)(smem + AS_B + WS_B);

    const int tid  = threadIdx.x;
    const int wave = tid >> 6;
    const int lane = tid & 63;
    const int quad = lane >> 4;
    const int l16  = lane & 15;
    const int wm   = wave / WGN;
    const int wn   = wave % WGN;
    const int pu0  = blockIdx.x * P;
    const int n0   = blockIdx.y * BN;
    const int vmask_out = (1 << vshift_out) - 1;

    // ---- one-time index setup: gidx[r][s] = (b<<vshift_in) + spiral[v][s] ----
    if (tid < R) {
        int r  = tid;
        int ul = r / 3;
        int kp = r - ul*3;
        int pu = pu0 + ul;
        int b  = pu >> vshift_out;
        int u  = pu & vmask_out;
        int v  = didx[u*3 + kp];
        int base = b << vshift_in;
        const int* svp = spiral + v*12;
        int4 s0 = *(const int4*)(svp);
        int4 s1 = *(const int4*)(svp + 4);
        int4 s2 = *(const int4*)(svp + 8);
        int* gp = gidx + r*12;
        gp[0]=base+s0.x; gp[1]=base+s0.y; gp[2]=base+s0.z; gp[3]=base+s0.w;
        gp[4]=base+s1.x; gp[5]=base+s1.y; gp[6]=base+s1.z; gp[7]=base+s1.w;
        gp[8]=base+s2.x; gp[9]=base+s2.y; gp[10]=base+s2.z; gp[11]=base+s2.w;
    }
    __syncthreads();

    f32x4 acc[NMT][NNT];
    #pragma unroll
    for (int i = 0; i < NMT; ++i)
        #pragma unroll
        for (int j = 0; j < NNT; ++j) acc[i][j] = (f32x4){0.f, 0.f, 0.f, 0.f};

    for (int t = 0; t < KT; ++t) {
        // ---- stage A: contiguous per-row gather ----
        #pragma unroll
        for (int e = tid; e < R*8; e += 256) {
            int r  = e >> 3;
            int kc = e & 7;
            int k  = t*64 + kc*8;
            int flat = gidx[r*12 + k/C_IN];
            int c  = k & (C_IN - 1);
            *(f16x8*)&As[(r*9 + kc)*8] = *(const f16x8*)&x[(size_t)flat*C_IN + c];
        }
        // ---- stage W: flat coalesced copy of this (y, t) tile ----
        {
            const _Float16* wsrc = Wp + (size_t)(blockIdx.y*KT + t)*(64*BN);
            #pragma unroll
            for (int e = tid; e < BN*8; e += 256)
                *(f16x8*)&Ws[e*8] = *(const f16x8*)&wsrc[e*8];
        }
        __syncthreads();

        #pragma unroll
        for (int kt = 0; kt < 2; ++kt) {
            f16x8 af[NMT], bf[NNT];
            #pragma unroll
            for (int i = 0; i < NMT; ++i) {
                int m_local = wm*WTM + i*16 + l16;
                af[i] = *(const f16x8*)&As[(m_local*9 + kt*4 + quad)*8];
            }
            #pragma unroll
            for (int j = 0; j < NNT; ++j) {
                int n_local = wn*WTN + j*16 + l16;
                bf[j] = *(const f16x8*)&Ws[((kt*4 + quad)*BN + n_local)*8];
            }
            #pragma unroll
            for (int i = 0; i < NMT; ++i)
                #pragma unroll
                for (int j = 0; j < NNT; ++j)
                    acc[i][j] = __builtin_amdgcn_mfma_f32_16x16x32_f16(
                        af[i], bf[j], acc[i][j], 0, 0, 0);
        }
        __syncthreads();
    }

    // ---- epilogue: bias+ELU rows into LDS, then 3-row weighted combine ----
    float* E = (float*)smem;
    float bv[NNT];
    #pragma unroll
    for (int j = 0; j < NNT; ++j)
        bv[j] = bias[n0 + wn*WTN + j*16 + l16];

    #pragma unroll
    for (int i = 0; i < NMT; ++i) {
        int row_base = wm*WTM + i*16 + quad*4;
        #pragma unroll
        for (int j = 0; j < NNT; ++j) {
            int col = wn*WTN + j*16 + l16;
            #pragma unroll
            for (int r = 0; r < 4; ++r)
                E[(size_t)(row_base + r)*(BN+4) + col] = elu_f(acc[i][j][r] + bv[j]);
        }
    }
    __syncthreads();

    const float4* E4 = (const float4*)smem;
    #pragma unroll
    for (int e = tid; e < P*C4; e += 256) {
        int ul = e / C4;
        int c4 = e - ul*C4;
        int pu = pu0 + ul;
        int u  = pu & vmask_out;
        const float* w = dwt + u*3;
        float4 a0 = E4[(size_t)(ul*3 + 0)*(C4+1) + c4];
        float4 a1 = E4[(size_t)(ul*3 + 1)*(C4+1) + c4];
        float4 a2 = E4[(size_t)(ul*3 + 2)*(C4+1) + c4];
        float ox = w[0]*a0.x + w[1]*a1.x + w[2]*a2.x;
        float oy = w[0]*a0.y + w[1]*a1.y + w[2]*a2.y;
        float oz = w[0]*a0.z + w[1]*a1.z + w[2]*a2.z;
        float ow = w[0]*a0.w + w[1]*a1.w + w[2]*a2.w;
        if (OUT_HALF) {
            f16x4 h; h[0]=(_Float16)ox; h[1]=(_Float16)oy; h[2]=(_Float16)oz; h[3]=(_Float16)ow;
            *(f16x4*)&((_Float16*)outv)[(size_t)pu*C_OUT + n0 + c4*4] = h;
        } else {
            float4 o; o.x=ox; o.y=oy; o.z=oz; o.w=ow;
            *(float4*)&((float*)outv)[(size_t)pu*C_OUT + n0 + c4*4] = o;
        }
    }
}

// ---------------- fused conv0+pool0 (fp16 padded x, K=48 padded to 64) ----------------
// P=64, R=192, BN=32. b is uniform per block (64 divides 8192).
__global__ __launch_bounds__(256)
void conv0_pool_mfma(const _Float16* __restrict__ xh4, const int* __restrict__ spiral,
                     const _Float16* __restrict__ Wp, const float* __restrict__ bias,
                     const int* __restrict__ didx, const float* __restrict__ dwt,
                     _Float16* __restrict__ out)
{
    constexpr int P = 64, R = 192, BN = 32;
    constexpr int NMT = 3, NNT = 2;        // 4 waves x (48 rows, 32 cols)
    constexpr int C4 = BN/4;
    constexpr int AS_B = R*9*8*2;          // 27648
    constexpr int WS_B = 64*BN*2;          // 4096
    constexpr int VR_B = R*4;              // 768
    constexpr int STAGE_B = AS_B + WS_B + VR_B;
    constexpr int EPI_B   = R*(BN+4)*4;    // 27648
    constexpr int SMEM_B  = STAGE_B > EPI_B ? STAGE_B : EPI_B;
    __shared__ char smem[SMEM_B] __attribute__((aligned(16)));
    _Float16* As = (_Float16*)smem;
    _Float16* Ws = (_Float16*)(smem + AS_B);
    int* vrow    = (int*)(smem + AS_B + WS_B);

    const int tid  = threadIdx.x;
    const int wave = tid >> 6;
    const int lane = tid & 63;
    const int quad = lane >> 4;
    const int l16  = lane & 15;
    const int pu0  = blockIdx.x * P;
    const int b    = pu0 >> 13;
    const int base = b << 15;

    if (tid < R) {
        int ul = tid / 3;
        int kp = tid - ul*3;
        int u  = (pu0 + ul) & 8191;
        vrow[tid] = didx[u*3 + kp];
    }
    if (tid < 256) {
        *(f16x8*)&Ws[tid*8] = *(const f16x8*)&Wp[tid*8];
    }
    __syncthreads();

    // stage A: chunks kc 0..5 = spiral vert pairs (4ch padded), 6..7 zero
    #pragma unroll
    for (int e = tid; e < R*8; e += 256) {
        int r  = e >> 3;
        int kc = e & 7;
        f16x8 h = (f16x8){0,0,0,0,0,0,0,0};
        if (kc < 6) {
            int v  = vrow[r];
            int g0 = spiral[v*12 + kc*2];
            int g1 = spiral[v*12 + kc*2 + 1];
            f16x4 a = *(const f16x4*)&xh4[(size_t)(base + g0)*4];
            f16x4 c = *(const f16x4*)&xh4[(size_t)(base + g1)*4];
            h[0]=a[0]; h[1]=a[1]; h[2]=a[2]; h[3]=a[3];
            h[4]=c[0]; h[5]=c[1]; h[6]=c[2]; h[7]=c[3];
        }
        *(f16x8*)&As[(r*9 + kc)*8] = h;
    }
    __syncthreads();

    f32x4 acc[NMT][NNT];
    #pragma unroll
    for (int i = 0; i < NMT; ++i)
        #pragma unroll
        for (int j = 0; j < NNT; ++j) acc[i][j] = (f32x4){0.f, 0.f, 0.f, 0.f};

    #pragma unroll
    for (int kt = 0; kt < 2; ++kt) {
        f16x8 af[NMT], bf[NNT];
        #pragma unroll
        for (int i = 0; i < NMT; ++i) {
            int m_local = wave*48 + i*16 + l16;
            af[i] = *(const f16x8*)&As[(m_local*9 + kt*4 + quad)*8];
        }
        #pragma unroll
        for (int j = 0; j < NNT; ++j) {
            int n_local = j*16 + l16;
            bf[j] = *(const f16x8*)&Ws[((kt*4 + quad)*BN + n_local)*8];
        }
        #pragma unroll
        for (int i = 0; i < NMT; ++i)
            #pragma unroll
            for (int j = 0; j < NNT; ++j)
                acc[i][j] = __builtin_amdgcn_mfma_f32_16x16x32_f16(
                    af[i], bf[j], acc[i][j], 0, 0, 0);
    }
    __syncthreads();

    float* E = (float*)smem;
    float bv[NNT];
    #pragma unroll
    for (int j = 0; j < NNT; ++j) bv[j] = bias[j*16 + l16];

    #pragma unroll
    for (int i = 0; i < NMT; ++i) {
        int row_base = wave*48 + i*16 + quad*4;
        #pragma unroll
        for (int j = 0; j < NNT; ++j) {
            int col = j*16 + l16;
            #pragma unroll
            for (int r = 0; r < 4; ++r)
                E[(size_t)(row_base + r)*(BN+4) + col] = elu_f(acc[i][j][r] + bv[j]);
        }
    }
    __syncthreads();

    const float4* E4 = (const float4*)smem;
    #pragma unroll
    for (int e = tid; e < P*C4; e += 256) {
        int ul = e / C4;
        int c4 = e - ul*C4;
        int pu = pu0 + ul;
        int u  = pu & 8191;
        const float* w = dwt + u*3;
        float4 a0 = E4[(size_t)(ul*3 + 0)*(C4+1) + c4];
        float4 a1 = E4[(size_t)(ul*3 + 1)*(C4+1) + c4];
        float4 a2 = E4[(size_t)(ul*3 + 2)*(C4+1) + c4];
        f16x4 h;
        h[0] = (_Float16)(w[0]*a0.x + w[1]*a1.x + w[2]*a2.x);
        h[1] = (_Float16)(w[0]*a0.y + w[1]*a1.y + w[2]*a2.y);
        h[2] = (_Float16)(w[0]*a0.z + w[1]*a1.z + w[2]*a2.z);
        h[3] = (_Float16)(w[0]*a0.w + w[1]*a1.w + w[2]*a2.w);
        *(f16x4*)&out[(size_t)pu*BN + c4*4] = h;
    }
}

// ---------------- FC1: atomic-free split-K ----------------
// grid (4 n-tiles of 128, 128 k-splits of 256). Thread = (mh, kq, n4):
// acc[16][4]; LDS tree-reduce over kq; one non-atomic partial write per block.
__global__ __launch_bounds__(256)
void fc1_partial(const float* __restrict__ xflat, const float* __restrict__ Wl1,
                 float* __restrict__ partial)
{
    __shared__ float sb[8704];   // xs[32][256] then reduce scratch [128][68]
    const int tid = threadIdx.x;
    const int n4 = tid & 31;
    const int kq = (tid >> 5) & 3;
    const int mh = tid >> 7;
    const int nt = blockIdx.x;
    const int ks = blockIdx.y;
    const int kbase = ks * 256;

    for (int e = tid; e < 2048; e += 256) {
        int m = e >> 6, k4 = e & 63;
        *(float4*)&sb[m*256 + k4*4] = *(const float4*)&xflat[(size_t)m*32768 + kbase + k4*4];
    }
    __syncthreads();

    float acc[16][4];
    #pragma unroll
    for (int m = 0; m < 16; ++m)
        #pragma unroll
        for (int c = 0; c < 4; ++c) acc[m][c] = 0.0f;

    const float* Wb = Wl1 + (size_t)(kbase + kq*64)*512 + nt*128 + n4*4;
    #pragma unroll 2
    for (int i = 0; i < 64; i += 4) {
        float4 w0 = *(const float4*)(Wb + (size_t)(i+0)*512);
        float4 w1 = *(const float4*)(Wb + (size_t)(i+1)*512);
        float4 w2 = *(const float4*)(Wb + (size_t)(i+2)*512);
        float4 w3 = *(const float4*)(Wb + (size_t)(i+3)*512);
        #pragma unroll
        for (int m = 0; m < 16; ++m) {
            float4 xv = *(const float4*)&sb[(mh*16 + m)*256 + kq*64 + i];
            acc[m][0] += xv.x*w0.x + xv.y*w1.x + xv.z*w2.x + xv.w*w3.x;
            acc[m][1] += xv.x*w0.y + xv.y*w1.y + xv.z*w2.y + xv.w*w3.y;
            acc[m][2] += xv.x*w0.z + xv.y*w1.z + xv.z*w2.z + xv.w*w3.z;
            acc[m][3] += xv.x*w0.w + xv.y*w1.w + xv.z*w2.w + xv.w*w3.w;
        }
    }
    __syncthreads();   // xs dead, reuse sb as reduce scratch (stride 68: conflict-free)

    // phase 1: kq {1,3} -> kq {0,2}
    int slot = (mh*2 + (kq >> 1))*32 + n4;
    if (kq & 1) {
        #pragma unroll
        for (int m = 0; m < 16; ++m)
            *(float4*)&sb[slot*68 + m*4] = *(float4*)&acc[m][0];
    }
    __syncthreads();
    if (!(kq & 1)) {
        #pragma unroll
        for (int m = 0; m < 16; ++m) {
            float4 v = *(const float4*)&sb[slot*68 + m*4];
            acc[m][0] += v.x; acc[m][1] += v.y; acc[m][2] += v.z; acc[m][3] += v.w;
        }
    }
    __syncthreads();
    // phase 2: kq 2 -> kq 0
    int slot2 = mh*32 + n4;
    if (kq == 2) {
        #pragma unroll
        for (int m = 0; m < 16; ++m)
            *(float4*)&sb[slot2*68 + m*4] = *(float4*)&acc[m][0];
    }
    __syncthreads();
    if (kq == 0) {
        float* pb = partial + ((size_t)(ks*4 + nt)*32 + mh*16)*128 + n4*4;
        #pragma unroll
        for (int m = 0; m < 16; ++m) {
            float4 v = *(const float4*)&sb[slot2*68 + m*4];
            float4 o;
            o.x = acc[m][0] + v.x; o.y = acc[m][1] + v.y;
            o.z = acc[m][2] + v.z; o.w = acc[m][3] + v.w;
            *(float4*)(pb + (size_t)m*128) = o;
        }
    }
}

__global__ __launch_bounds__(256)
void fc1_reduce(const float* __restrict__ partial, const float* __restrict__ bl1,
                float* __restrict__ hout)
{
    int i = blockIdx.x * 256 + threadIdx.x;   // 16384
    int m = i >> 9, n = i & 511;
    int nt = n >> 7, nl = n & 127;
    const float* p = partial + ((size_t)nt*32 + m)*128 + nl;
    float s = 0.0f;
    #pragma unroll 8
    for (int ks = 0; ks < 128; ++ks)
        s += p[(size_t)ks*4*4096];
    hout[i] = elu_f(s + bl1[n]);
}

__global__ __launch_bounds__(64)
void fc2_kernel(const float* __restrict__ h, const float* __restrict__ Wl2,
                const float* __restrict__ bl2, float* __restrict__ y)
{
    int m = blockIdx.x;
    int n = threadIdx.x;
    float s = bl2[n];
    for (int k = 0; k < 512; ++k)
        s += h[(size_t)m*512 + k] * Wl2[(size_t)k*64 + n];
    y[(size_t)m*64 + n] = s;
}

extern "C" void kernel_launch(void* const* d_in, const int* in_sizes, int n_in,
                              void* d_out, int out_size, void* d_ws, size_t ws_size,
                              hipStream_t stream)
{
    (void)in_sizes; (void)n_in; (void)out_size;

    const float* x0 = (const float*)d_in[0];
    const int*   sp[4]; const int* didx[4]; const float* dwp[4];
    const float* Wp[4]; const float* bp[4];
    for (int i = 0; i < 4; ++i) {
        sp[i]   = (const int*)  d_in[1 + i*5 + 0];
        didx[i] = (const int*)  d_in[1 + i*5 + 1];
        dwp[i]  = (const float*)d_in[1 + i*5 + 2];
        Wp[i]   = (const float*)d_in[1 + i*5 + 3];
        bp[i]   = (const float*)d_in[1 + i*5 + 4];
    }
    const float* Wl1 = (const float*)d_in[21];
    const float* bl1 = (const float*)d_in[22];
    const float* Wl2 = (const float*)d_in[23];
    const float* bl2 = (const float*)d_in[24];
    float* out = (float*)d_out;

    char* wsb = (char*)d_ws;
    float* persist   = (float*)wsb;                      // 4 MB (32,128,256) fp32
    float* partial   = (float*)(wsb + 4194304);          // 8.4 MB: 512 x 4096 floats
    _Float16* w0h    = (_Float16*)(wsb + 12582912);      //   2,048 halfs
    _Float16* w1h    = w0h + 2048;                       //  24,576 halfs
    _Float16* w2h    = w1h + 24576;                      //  98,304 halfs
    _Float16* w3h    = w2h + 98304;                      // 393,216 halfs
    char* bufs       = wsb + 13619200;

    // per-batch-unit: xh4 256K + pooled0 512K + pooled1 256K + pooled2 128K = 1,179,648 B
    int Bc = 32;
    while (Bc > 1 && (size_t)13619200 + (size_t)Bc*1179648ULL > ws_size)
        Bc >>= 1;
    _Float16* xh4     = (_Float16*)bufs;
    _Float16* pooled0 = xh4 + (size_t)Bc*131072ULL;      // Bc*32768*4 halfs
    _Float16* pooled1 = pooled0 + (size_t)Bc*262144ULL;  // Bc*8192*32
    _Float16* pooled2 = pooled1 + (size_t)Bc*131072ULL;  // Bc*2048*64

    prep_w0<<<8, 256, 0, stream>>>(Wp[0], w0h);
    prep_w< 384,  64,  64><<<( 24576 + 255)/256, 256, 0, stream>>>(Wp[1], w1h);
    prep_w< 768, 128, 128><<<( 98304 + 255)/256, 256, 0, stream>>>(Wp[2], w2h);
    prep_w<1536, 256,  64><<<(393216 + 255)/256, 256, 0, stream>>>(Wp[3], w3h);

    for (int b0 = 0; b0 < 32; b0 += Bc) {
        const float* xin = x0 + (size_t)b0*32768*3;

        prep_x<<<(Bc*32768 + 255)/256, 256, 0, stream>>>(xin, xh4, Bc*32768);

        // L0: conv(4->32, K=48 pad 64) + pool -> fp16 (Bc, 8192, 32)
        conv0_pool_mfma<<<Bc*8192/64, 256, 0, stream>>>(
            xh4, sp[0], w0h, bp[0], didx[0], dwp[0], pooled0);

        // L1: conv(32->64, K=384) + pool -> fp16 (Bc, 2048, 64)
        conv_pool_mfma<32,64,64,64,4,1,true><<<Bc*2048/64, 256, 0, stream>>>(
            pooled0, sp[1], w1h, bp[1], didx[1], dwp[1], pooled1, 13, 11);

        // L2: conv(64->128, K=768) + pool -> fp16 (Bc, 512, 128)
        conv_pool_mfma<64,128,32,128,2,2,true><<<Bc*512/32, 256, 0, stream>>>(
            pooled1, sp[2], w2h, bp[2], didx[2], dwp[2], pooled2, 11, 9);

        // L3: conv(128->256, K=1536) + pool -> fp32 persist (Bc, 128, 256)
        conv_pool_mfma<128,256,32,64,2,2,false><<<dim3(Bc*128/32, 4), 256, 0, stream>>>(
            pooled2, sp[3], w3h, bp[3], didx[3], dwp[3],
            persist + (size_t)b0*32768, 9, 7);
    }

    // FC1: (32,32768)@(32768,512), split-K partials then reduce+bias+ELU
    fc1_partial<<<dim3(4, 128), 256, 0, stream>>>(persist, Wl1, partial);
    fc1_reduce<<<64, 256, 0, stream>>>(partial, bl1, out);

    // FC2: (32,512)@(512,64) + bias -> d_out[16384:18432]
    fc2_kernel<<<32, 64, 0, stream>>>(out, Wl2, bl2, out + 16384);
}

// Round 6
// 368.204 us; speedup vs baseline: 1.4484x; 1.0727x over previous
//
#include <hip/hip_runtime.h>
#include <cstdint>
#include <cstddef>

typedef _Float16 f16x8 __attribute__((ext_vector_type(8)));
typedef _Float16 f16x4 __attribute__((ext_vector_type(4)));
typedef float f32x4 __attribute__((ext_vector_type(4)));

static __device__ __forceinline__ float elu_f(float t) {
    return t > 0.0f ? t : expm1f(t);
}

// XCD-aware block -> pooled-vertex-tile remap. Heuristic: XCD = bid & 7
// (round-robin dispatch). Pin batches {xcd, xcd+8, ...} to one XCD so the
// random spiral gathers hit that XCD's L2 (batch slice <= 512 KB).
static __device__ __forceinline__ int block_pu0(int bid, int P, int vshift_out, int nbl)
{
    if (nbl < 0) return bid * P;
    int xcd  = bid & 7;
    int slot = bid >> 3;
    int nb   = slot & ((1 << nbl) - 1);
    int tile = slot >> nbl;
    return ((xcd + (nb << 3)) << vshift_out) + tile * P;
}

// ---------------- x prep: fp32 (B,V,3) -> fp16 (B,V,4) zero-padded ----------------
__global__ __launch_bounds__(256)
void prep_x(const float* __restrict__ x, _Float16* __restrict__ xh4, int total)
{
    int i = blockIdx.x * 256 + threadIdx.x;
    if (i >= total) return;
    const float* p = x + (size_t)i*3;
    f16x4 h;
    h[0] = (_Float16)p[0]; h[1] = (_Float16)p[1]; h[2] = (_Float16)p[2]; h[3] = (_Float16)0.f;
    *(f16x4*)&xh4[(size_t)i*4] = h;
}

// ---------------- weight prep: fp32 [K][C_OUT] -> fp16 tiled [y][t][kc][n][8] ----------------
template<int KTOT, int C_OUT, int BN>
__global__ __launch_bounds__(256)
void prep_w(const float* __restrict__ W, _Float16* __restrict__ o)
{
    constexpr int KT = KTOT/64;
    int i = blockIdx.x * 256 + threadIdx.x;
    if (i >= KTOT*C_OUT) return;
    int j = i & 7;
    int rest = i >> 3;
    int n = rest % BN;
    int kc = (rest / BN) & 7;
    int t = (rest / (BN*8)) % KT;
    int y = rest / (BN*8*KT);
    int k = t*64 + kc*8 + j;
    o[i] = (_Float16)W[(size_t)k*C_OUT + y*BN + n];
}

// Level-0 weights: (36,32) -> padded K=64, k = s*4 + c layout, tile [kc][n][8]
__global__ __launch_bounds__(256)
void prep_w0(const float* __restrict__ W, _Float16* __restrict__ o)
{
    int i = blockIdx.x * 256 + threadIdx.x;
    if (i >= 2048) return;
    int j = i & 7;
    int n = (i >> 3) & 31;
    int kc = i >> 8;
    int k = kc*8 + j;
    int s = k >> 2, c = k & 3;
    float v = (s < 12 && c < 3) ? W[(size_t)(s*3 + c)*32 + n] : 0.0f;
    o[i] = (_Float16)v;
}

// ---------------- fused conv+pool, MFMA fp16, levels 1-3 ----------------
// As layout [r][9 chunks][8 halfs]; gidx = ushort spiral table (block is
// single-batch, base uniform), hoisted once; staging reads per-row
// contiguous 64-k tiles (C_IN>=64: one 128B block; C_IN=32: two 64B).
template<int C_IN, int C_OUT, int P, int BN, int WGM, int WGN, bool OUT_HALF>
__global__ __launch_bounds__(256)
void conv_pool_mfma(const _Float16* __restrict__ x, const int* __restrict__ spiral,
                    const _Float16* __restrict__ Wp, const float* __restrict__ bias,
                    const int* __restrict__ didx, const float* __restrict__ dwt,
                    void* __restrict__ outv, int vshift_in, int vshift_out, int nbl)
{
    constexpr int R    = 3*P;
    constexpr int KTOT = 12*C_IN;
    constexpr int KT   = KTOT/64;
    constexpr int WTM  = R/WGM;
    constexpr int WTN  = BN/WGN;
    constexpr int NMT  = WTM/16;
    constexpr int NNT  = WTN/16;
    constexpr int C4   = BN/4;
    constexpr int AS_B = R*9*8*2;
    constexpr int WS_B = 64*BN*2;
    constexpr int GI_B = R*12*2;
    constexpr int STAGE_B = AS_B + WS_B + GI_B;
    constexpr int EPI_B   = R*(BN+4)*2;
    constexpr int SMEM_B  = STAGE_B > EPI_B ? STAGE_B : EPI_B;
    static_assert(WTM % 16 == 0 && WTN % 16 == 0, "tile");
    static_assert((R*8) % 256 == 0 && (P*C4) % 256 == 0, "loops");

    __shared__ char smem[SMEM_B] __attribute__((aligned(16)));
    _Float16* As = (_Float16*)smem;
    _Float16* Ws = (_Float16*)(smem + AS_B);
    unsigned short* gidx = (unsigned short*)(smem + AS_B + WS_B);

    const int tid  = threadIdx.x;
    const int wave = tid >> 6;
    const int lane = tid & 63;
    const int quad = lane >> 4;
    const int l16  = lane & 15;
    const int wm   = wave / WGN;
    const int wn   = wave % WGN;
    const int pu0  = block_pu0(blockIdx.x, P, vshift_out, nbl);
    const int n0   = blockIdx.y * BN;
    const int vmask_out = (1 << vshift_out) - 1;
    const int base_in = (pu0 >> vshift_out) << vshift_in;   // block-uniform batch base

    // ---- one-time index setup: gidx[r][s] = spiral[didx[u][kp]][s] (u16) ----
    if (tid < R) {
        int ul = tid / 3;
        int kp = tid - ul*3;
        int u  = (pu0 + ul) & vmask_out;
        int v  = didx[u*3 + kp];
        const int* svp = spiral + v*12;
        unsigned short* gp = gidx + tid*12;
        #pragma unroll
        for (int j = 0; j < 12; ++j) gp[j] = (unsigned short)svp[j];
    }
    __syncthreads();

    f32x4 acc[NMT][NNT];
    #pragma unroll
    for (int i = 0; i < NMT; ++i)
        #pragma unroll
        for (int j = 0; j < NNT; ++j) acc[i][j] = (f32x4){0.f, 0.f, 0.f, 0.f};

    for (int t = 0; t < KT; ++t) {
        // ---- stage A: contiguous per-row gather ----
        #pragma unroll
        for (int e = tid; e < R*8; e += 256) {
            int r  = e >> 3;
            int kc = e & 7;
            int k  = t*64 + kc*8;
            int g  = gidx[r*12 + k/C_IN];
            int c  = k & (C_IN - 1);
            *(f16x8*)&As[(r*9 + kc)*8] = *(const f16x8*)&x[(size_t)(base_in + g)*C_IN + c];
        }
        // ---- stage W: flat coalesced copy of this (y, t) tile ----
        {
            const _Float16* wsrc = Wp + (size_t)(blockIdx.y*KT + t)*(64*BN);
            #pragma unroll
            for (int e = tid; e < BN*8; e += 256)
                *(f16x8*)&Ws[e*8] = *(const f16x8*)&wsrc[e*8];
        }
        __syncthreads();

        #pragma unroll
        for (int kt = 0; kt < 2; ++kt) {
            f16x8 af[NMT], bf[NNT];
            #pragma unroll
            for (int i = 0; i < NMT; ++i) {
                int m_local = wm*WTM + i*16 + l16;
                af[i] = *(const f16x8*)&As[(m_local*9 + kt*4 + quad)*8];
            }
            #pragma unroll
            for (int j = 0; j < NNT; ++j) {
                int n_local = wn*WTN + j*16 + l16;
                bf[j] = *(const f16x8*)&Ws[((kt*4 + quad)*BN + n_local)*8];
            }
            #pragma unroll
            for (int i = 0; i < NMT; ++i)
                #pragma unroll
                for (int j = 0; j < NNT; ++j)
                    acc[i][j] = __builtin_amdgcn_mfma_f32_16x16x32_f16(
                        af[i], bf[j], acc[i][j], 0, 0, 0);
        }
        __syncthreads();
    }

    // ---- epilogue: bias+ELU rows into LDS (fp16), then 3-row weighted combine ----
    _Float16* E = (_Float16*)smem;
    float bv[NNT];
    #pragma unroll
    for (int j = 0; j < NNT; ++j)
        bv[j] = bias[n0 + wn*WTN + j*16 + l16];

    #pragma unroll
    for (int i = 0; i < NMT; ++i) {
        int row_base = wm*WTM + i*16 + quad*4;
        #pragma unroll
        for (int j = 0; j < NNT; ++j) {
            int col = wn*WTN + j*16 + l16;
            #pragma unroll
            for (int r = 0; r < 4; ++r)
                E[(size_t)(row_base + r)*(BN+4) + col] =
                    (_Float16)elu_f(acc[i][j][r] + bv[j]);
        }
    }
    __syncthreads();

    #pragma unroll
    for (int e = tid; e < P*C4; e += 256) {
        int ul = e / C4;
        int c4 = e - ul*C4;
        int pu = pu0 + ul;
        int u  = pu & vmask_out;
        const float* w = dwt + u*3;
        f16x4 a0 = *(const f16x4*)&E[(size_t)(ul*3 + 0)*(BN+4) + c4*4];
        f16x4 a1 = *(const f16x4*)&E[(size_t)(ul*3 + 1)*(BN+4) + c4*4];
        f16x4 a2 = *(const f16x4*)&E[(size_t)(ul*3 + 2)*(BN+4) + c4*4];
        float ox = w[0]*(float)a0[0] + w[1]*(float)a1[0] + w[2]*(float)a2[0];
        float oy = w[0]*(float)a0[1] + w[1]*(float)a1[1] + w[2]*(float)a2[1];
        float oz = w[0]*(float)a0[2] + w[1]*(float)a1[2] + w[2]*(float)a2[2];
        float ow = w[0]*(float)a0[3] + w[1]*(float)a1[3] + w[2]*(float)a2[3];
        if (OUT_HALF) {
            f16x4 h; h[0]=(_Float16)ox; h[1]=(_Float16)oy; h[2]=(_Float16)oz; h[3]=(_Float16)ow;
            *(f16x4*)&((_Float16*)outv)[(size_t)pu*C_OUT + n0 + c4*4] = h;
        } else {
            float4 o; o.x=ox; o.y=oy; o.z=oz; o.w=ow;
            *(float4*)&((float*)outv)[(size_t)pu*C_OUT + n0 + c4*4] = o;
        }
    }
}

// ---------------- fused conv0+pool0 (fp16 padded x, K=48 padded to 64) ----------------
// P=64, R=192, BN=32.
__global__ __launch_bounds__(256)
void conv0_pool_mfma(const _Float16* __restrict__ xh4, const int* __restrict__ spiral,
                     const _Float16* __restrict__ Wp, const float* __restrict__ bias,
                     const int* __restrict__ didx, const float* __restrict__ dwt,
                     _Float16* __restrict__ out, int nbl)
{
    constexpr int P = 64, R = 192, BN = 32;
    constexpr int NMT = 3, NNT = 2;        // 4 waves x (48 rows, 32 cols)
    constexpr int C4 = BN/4;
    constexpr int AS_B = R*9*8*2;          // 27648
    constexpr int WS_B = 64*BN*2;          // 4096
    constexpr int VR_B = R*2;              // 384 (u16 vrow)
    constexpr int STAGE_B = AS_B + WS_B + VR_B;
    constexpr int EPI_B   = R*(BN+4)*2;    // 13824
    constexpr int SMEM_B  = STAGE_B > EPI_B ? STAGE_B : EPI_B;
    __shared__ char smem[SMEM_B] __attribute__((aligned(16)));
    _Float16* As = (_Float16*)smem;
    _Float16* Ws = (_Float16*)(smem + AS_B);
    unsigned short* vrow = (unsigned short*)(smem + AS_B + WS_B);

    const int tid  = threadIdx.x;
    const int wave = tid >> 6;
    const int lane = tid & 63;
    const int quad = lane >> 4;
    const int l16  = lane & 15;
    const int pu0  = block_pu0(blockIdx.x, P, 13, nbl);
    const int base = (pu0 >> 13) << 15;

    if (tid < R) {
        int ul = tid / 3;
        int kp = tid - ul*3;
        int u  = (pu0 + ul) & 8191;
        vrow[tid] = (unsigned short)didx[u*3 + kp];
    }
    if (tid < 256) {
        *(f16x8*)&Ws[tid*8] = *(const f16x8*)&Wp[tid*8];
    }
    __syncthreads();

    // stage A: chunks kc 0..5 = spiral vert pairs (4ch padded), 6..7 zero
    #pragma unroll
    for (int e = tid; e < R*8; e += 256) {
        int r  = e >> 3;
        int kc = e & 7;
        f16x8 h = (f16x8){0,0,0,0,0,0,0,0};
        if (kc < 6) {
            int v  = vrow[r];
            int2 g = *(const int2*)&spiral[v*12 + kc*2];
            f16x4 a = *(const f16x4*)&xh4[(size_t)(base + g.x)*4];
            f16x4 c = *(const f16x4*)&xh4[(size_t)(base + g.y)*4];
            h[0]=a[0]; h[1]=a[1]; h[2]=a[2]; h[3]=a[3];
            h[4]=c[0]; h[5]=c[1]; h[6]=c[2]; h[7]=c[3];
        }
        *(f16x8*)&As[(r*9 + kc)*8] = h;
    }
    __syncthreads();

    f32x4 acc[NMT][NNT];
    #pragma unroll
    for (int i = 0; i < NMT; ++i)
        #pragma unroll
        for (int j = 0; j < NNT; ++j) acc[i][j] = (f32x4){0.f, 0.f, 0.f, 0.f};

    #pragma unroll
    for (int kt = 0; kt < 2; ++kt) {
        f16x8 af[NMT], bf[NNT];
        #pragma unroll
        for (int i = 0; i < NMT; ++i) {
            int m_local = wave*48 + i*16 + l16;
            af[i] = *(const f16x8*)&As[(m_local*9 + kt*4 + quad)*8];
        }
        #pragma unroll
        for (int j = 0; j < NNT; ++j) {
            int n_local = j*16 + l16;
            bf[j] = *(const f16x8*)&Ws[((kt*4 + quad)*BN + n_local)*8];
        }
        #pragma unroll
        for (int i = 0; i < NMT; ++i)
            #pragma unroll
            for (int j = 0; j < NNT; ++j)
                acc[i][j] = __builtin_amdgcn_mfma_f32_16x16x32_f16(
                    af[i], bf[j], acc[i][j], 0, 0, 0);
    }
    __syncthreads();

    _Float16* E = (_Float16*)smem;
    float bv[NNT];
    #pragma unroll
    for (int j = 0; j < NNT; ++j) bv[j] = bias[j*16 + l16];

    #pragma unroll
    for (int i = 0; i < NMT; ++i) {
        int row_base = wave*48 + i*16 + quad*4;
        #pragma unroll
        for (int j = 0; j < NNT; ++j) {
            int col = j*16 + l16;
            #pragma unroll
            for (int r = 0; r < 4; ++r)
                E[(size_t)(row_base + r)*(BN+4) + col] =
                    (_Float16)elu_f(acc[i][j][r] + bv[j]);
        }
    }
    __syncthreads();

    #pragma unroll
    for (int e = tid; e < P*C4; e += 256) {
        int ul = e / C4;
        int c4 = e - ul*C4;
        int pu = pu0 + ul;
        int u  = pu & 8191;
        const float* w = dwt + u*3;
        f16x4 a0 = *(const f16x4*)&E[(size_t)(ul*3 + 0)*(BN+4) + c4*4];
        f16x4 a1 = *(const f16x4*)&E[(size_t)(ul*3 + 1)*(BN+4) + c4*4];
        f16x4 a2 = *(const f16x4*)&E[(size_t)(ul*3 + 2)*(BN+4) + c4*4];
        f16x4 h;
        h[0] = (_Float16)(w[0]*(float)a0[0] + w[1]*(float)a1[0] + w[2]*(float)a2[0]);
        h[1] = (_Float16)(w[0]*(float)a0[1] + w[1]*(float)a1[1] + w[2]*(float)a2[1]);
        h[2] = (_Float16)(w[0]*(float)a0[2] + w[1]*(float)a1[2] + w[2]*(float)a2[2]);
        h[3] = (_Float16)(w[0]*(float)a0[3] + w[1]*(float)a1[3] + w[2]*(float)a2[3]);
        *(f16x4*)&out[(size_t)pu*BN + c4*4] = h;
    }
}

// ---------------- FC1: atomic-free split-K ----------------
__global__ __launch_bounds__(256)
void fc1_partial(const float* __restrict__ xflat, const float* __restrict__ Wl1,
                 float* __restrict__ partial)
{
    __shared__ float sb[8704];   // xs[32][256] then reduce scratch [128][68]
    const int tid = threadIdx.x;
    const int n4 = tid & 31;
    const int kq = (tid >> 5) & 3;
    const int mh = tid >> 7;
    const int nt = blockIdx.x;
    const int ks = blockIdx.y;
    const int kbase = ks * 256;

    for (int e = tid; e < 2048; e += 256) {
        int m = e >> 6, k4 = e & 63;
        *(float4*)&sb[m*256 + k4*4] = *(const float4*)&xflat[(size_t)m*32768 + kbase + k4*4];
    }
    __syncthreads();

    float acc[16][4];
    #pragma unroll
    for (int m = 0; m < 16; ++m)
        #pragma unroll
        for (int c = 0; c < 4; ++c) acc[m][c] = 0.0f;

    const float* Wb = Wl1 + (size_t)(kbase + kq*64)*512 + nt*128 + n4*4;
    #pragma unroll 2
    for (int i = 0; i < 64; i += 4) {
        float4 w0 = *(const float4*)(Wb + (size_t)(i+0)*512);
        float4 w1 = *(const float4*)(Wb + (size_t)(i+1)*512);
        float4 w2 = *(const float4*)(Wb + (size_t)(i+2)*512);
        float4 w3 = *(const float4*)(Wb + (size_t)(i+3)*512);
        #pragma unroll
        for (int m = 0; m < 16; ++m) {
            float4 xv = *(const float4*)&sb[(mh*16 + m)*256 + kq*64 + i];
            acc[m][0] += xv.x*w0.x + xv.y*w1.x + xv.z*w2.x + xv.w*w3.x;
            acc[m][1] += xv.x*w0.y + xv.y*w1.y + xv.z*w2.y + xv.w*w3.y;
            acc[m][2] += xv.x*w0.z + xv.y*w1.z + xv.z*w2.z + xv.w*w3.z;
            acc[m][3] += xv.x*w0.w + xv.y*w1.w + xv.z*w2.w + xv.w*w3.w;
        }
    }
    __syncthreads();

    int slot = (mh*2 + (kq >> 1))*32 + n4;
    if (kq & 1) {
        #pragma unroll
        for (int m = 0; m < 16; ++m)
            *(float4*)&sb[slot*68 + m*4] = *(float4*)&acc[m][0];
    }
    __syncthreads();
    if (!(kq & 1)) {
        #pragma unroll
        for (int m = 0; m < 16; ++m) {
            float4 v = *(const float4*)&sb[slot*68 + m*4];
            acc[m][0] += v.x; acc[m][1] += v.y; acc[m][2] += v.z; acc[m][3] += v.w;
        }
    }
    __syncthreads();
    int slot2 = mh*32 + n4;
    if (kq == 2) {
        #pragma unroll
        for (int m = 0; m < 16; ++m)
            *(float4*)&sb[slot2*68 + m*4] = *(float4*)&acc[m][0];
    }
    __syncthreads();
    if (kq == 0) {
        float* pb = partial + ((size_t)(ks*4 + nt)*32 + mh*16)*128 + n4*4;
        #pragma unroll
        for (int m = 0; m < 16; ++m) {
            float4 v = *(const float4*)&sb[slot2*68 + m*4];
            float4 o;
            o.x = acc[m][0] + v.x; o.y = acc[m][1] + v.y;
            o.z = acc[m][2] + v.z; o.w = acc[m][3] + v.w;
            *(float4*)(pb + (size_t)m*128) = o;
        }
    }
}

__global__ __launch_bounds__(256)
void fc1_reduce(const float* __restrict__ partial, const float* __restrict__ bl1,
                float* __restrict__ hout)
{
    int i = blockIdx.x * 256 + threadIdx.x;   // 16384
    int m = i >> 9, n = i & 511;
    int nt = n >> 7, nl = n & 127;
    const float* p = partial + ((size_t)nt*32 + m)*128 + nl;
    float s = 0.0f;
    #pragma unroll 8
    for (int ks = 0; ks < 128; ++ks)
        s += p[(size_t)ks*4*4096];
    hout[i] = elu_f(s + bl1[n]);
}

__global__ __launch_bounds__(64)
void fc2_kernel(const float* __restrict__ h, const float* __restrict__ Wl2,
                const float* __restrict__ bl2, float* __restrict__ y)
{
    int m = blockIdx.x;
    int n = threadIdx.x;
    float s = bl2[n];
    for (int k = 0; k < 512; ++k)
        s += h[(size_t)m*512 + k] * Wl2[(size_t)k*64 + n];
    y[(size_t)m*64 + n] = s;
}

extern "C" void kernel_launch(void* const* d_in, const int* in_sizes, int n_in,
                              void* d_out, int out_size, void* d_ws, size_t ws_size,
                              hipStream_t stream)
{
    (void)in_sizes; (void)n_in; (void)out_size;

    const float* x0 = (const float*)d_in[0];
    const int*   sp[4]; const int* didx[4]; const float* dwp[4];
    const float* Wp[4]; const float* bp[4];
    for (int i = 0; i < 4; ++i) {
        sp[i]   = (const int*)  d_in[1 + i*5 + 0];
        didx[i] = (const int*)  d_in[1 + i*5 + 1];
        dwp[i]  = (const float*)d_in[1 + i*5 + 2];
        Wp[i]   = (const float*)d_in[1 + i*5 + 3];
        bp[i]   = (const float*)d_in[1 + i*5 + 4];
    }
    const float* Wl1 = (const float*)d_in[21];
    const float* bl1 = (const float*)d_in[22];
    const float* Wl2 = (const float*)d_in[23];
    const float* bl2 = (const float*)d_in[24];
    float* out = (float*)d_out;

    char* wsb = (char*)d_ws;
    float* persist   = (float*)wsb;                      // 4 MB (32,128,256) fp32
    float* partial   = (float*)(wsb + 4194304);          // 8.4 MB: 512 x 4096 floats
    _Float16* w0h    = (_Float16*)(wsb + 12582912);      //   2,048 halfs
    _Float16* w1h    = w0h + 2048;                       //  24,576 halfs
    _Float16* w2h    = w1h + 24576;                      //  98,304 halfs
    _Float16* w3h    = w2h + 98304;                      // 393,216 halfs
    char* bufs       = wsb + 13619200;

    // per-batch-unit: xh4 256K + pooled0 512K + pooled1 256K + pooled2 128K
    int Bc = 32;
    while (Bc > 1 && (size_t)13619200 + (size_t)Bc*1179648ULL > ws_size)
        Bc >>= 1;
    _Float16* xh4     = (_Float16*)bufs;
    _Float16* pooled0 = xh4 + (size_t)Bc*131072ULL;
    _Float16* pooled1 = pooled0 + (size_t)Bc*262144ULL;
    _Float16* pooled2 = pooled1 + (size_t)Bc*131072ULL;

    // XCD swizzle: NB = Bc/8 batches per XCD (requires Bc % 8 == 0)
    int nbl = (Bc == 32) ? 2 : (Bc == 16) ? 1 : (Bc == 8) ? 0 : -1;

    prep_w0<<<8, 256, 0, stream>>>(Wp[0], w0h);
    prep_w< 384,  64,  64><<<( 24576 + 255)/256, 256, 0, stream>>>(Wp[1], w1h);
    prep_w< 768, 128, 128><<<( 98304 + 255)/256, 256, 0, stream>>>(Wp[2], w2h);
    prep_w<1536, 256,  64><<<(393216 + 255)/256, 256, 0, stream>>>(Wp[3], w3h);

    for (int b0 = 0; b0 < 32; b0 += Bc) {
        const float* xin = x0 + (size_t)b0*32768*3;

        prep_x<<<(Bc*32768 + 255)/256, 256, 0, stream>>>(xin, xh4, Bc*32768);

        // L0: conv(4->32, K=48 pad 64) + pool -> fp16 (Bc, 8192, 32)
        conv0_pool_mfma<<<Bc*8192/64, 256, 0, stream>>>(
            xh4, sp[0], w0h, bp[0], didx[0], dwp[0], pooled0, nbl);

        // L1: conv(32->64, K=384) + pool -> fp16 (Bc, 2048, 64)
        conv_pool_mfma<32,64,64,64,4,1,true><<<Bc*2048/64, 256, 0, stream>>>(
            pooled0, sp[1], w1h, bp[1], didx[1], dwp[1], pooled1, 13, 11, nbl);

        // L2: conv(64->128, K=768) + pool -> fp16 (Bc, 512, 128)
        conv_pool_mfma<64,128,32,128,2,2,true><<<Bc*512/32, 256, 0, stream>>>(
            pooled1, sp[2], w2h, bp[2], didx[2], dwp[2], pooled2, 11, 9, nbl);

        // L3: conv(128->256, K=1536) + pool -> fp32 persist (Bc, 128, 256)
        conv_pool_mfma<128,256,32,64,2,2,false><<<dim3(Bc*128/32, 4), 256, 0, stream>>>(
            pooled2, sp[3], w3h, bp[3], didx[3], dwp[3],
            persist + (size_t)b0*32768, 9, 7, nbl);
    }

    // FC1: (32,32768)@(32768,512), split-K partials then reduce+bias+ELU
    fc1_partial<<<dim3(4, 128), 256, 0, stream>>>(persist, Wl1, partial);
    fc1_reduce<<<64, 256, 0, stream>>>(partial, bl1, out);

    // FC2: (32,512)@(512,64) + bias -> d_out[16384:18432]
    fc2_kernel<<<32, 64, 0, stream>>>(out, Wl2, bl2, out + 16384);
}

// Round 7
// 352.752 us; speedup vs baseline: 1.5118x; 1.0438x over previous
//
#include <hip/hip_runtime.h>
#include <cstdint>
#include <cstddef>

typedef _Float16 f16x8 __attribute__((ext_vector_type(8)));
typedef _Float16 f16x4 __attribute__((ext_vector_type(4)));
typedef float f32x4 __attribute__((ext_vector_type(4)));

static __device__ __forceinline__ float elu_f(float t) {
    return t > 0.0f ? t : expm1f(t);
}

// XCD-aware block -> pooled-vertex-tile remap (XCD = bid & 7 round-robin).
static __device__ __forceinline__ int block_pu0(int bid, int P, int vshift_out, int nbl)
{
    if (nbl < 0) return bid * P;
    int xcd  = bid & 7;
    int slot = bid >> 3;
    int nb   = slot & ((1 << nbl) - 1);
    int tile = slot >> nbl;
    return ((xcd + (nb << 3)) << vshift_out) + tile * P;
}

// ---------------- x prep: fp32 (B,V,3) -> fp16 (B,V,4) zero-padded ----------------
__global__ __launch_bounds__(256)
void prep_x(const float* __restrict__ x, _Float16* __restrict__ xh4, int total)
{
    int i = blockIdx.x * 256 + threadIdx.x;
    if (i >= total) return;
    const float* p = x + (size_t)i*3;
    f16x4 h;
    h[0] = (_Float16)p[0]; h[1] = (_Float16)p[1]; h[2] = (_Float16)p[2]; h[3] = (_Float16)0.f;
    *(f16x4*)&xh4[(size_t)i*4] = h;
}

// ---------------- weight prep: fp32 [K][C_OUT] -> fp16 tiled [y][t][kc][n][8] ----------------
template<int KTOT, int C_OUT, int BN>
__global__ __launch_bounds__(256)
void prep_w(const float* __restrict__ W, _Float16* __restrict__ o)
{
    constexpr int KT = KTOT/64;
    int i = blockIdx.x * 256 + threadIdx.x;
    if (i >= KTOT*C_OUT) return;
    int j = i & 7;
    int rest = i >> 3;
    int n = rest % BN;
    int kc = (rest / BN) & 7;
    int t = (rest / (BN*8)) % KT;
    int y = rest / (BN*8*KT);
    int k = t*64 + kc*8 + j;
    o[i] = (_Float16)W[(size_t)k*C_OUT + y*BN + n];
}

// Level-0 weights: (36,32) -> padded K=64, k = s*4 + c layout, tile [kc][n][8]
__global__ __launch_bounds__(256)
void prep_w0(const float* __restrict__ W, _Float16* __restrict__ o)
{
    int i = blockIdx.x * 256 + threadIdx.x;
    if (i >= 2048) return;
    int j = i & 7;
    int n = (i >> 3) & 31;
    int kc = i >> 8;
    int k = kc*8 + j;
    int s = k >> 2, c = k & 3;
    float v = (s < 12 && c < 3) ? W[(size_t)(s*3 + c)*32 + n] : 0.0f;
    o[i] = (_Float16)v;
}

// ---------------- fused conv+pool, direct-to-register MFMA, levels 1-3 ----------------
// No A/W LDS staging: each lane gathers its own 16 B A-fragment chunk via the
// block's u16 spiral table, and loads its B-fragment straight from the
// pre-tiled Wp (coalesced, L1/L2-resident). LDS = index table + pool epilogue.
template<int C_IN, int C_OUT, int P, int BN, int WGM, int WGN, bool OUT_HALF>
__global__ __launch_bounds__(256)
void conv_pool_mfma(const _Float16* __restrict__ x, const int* __restrict__ spiral,
                    const _Float16* __restrict__ Wp, const float* __restrict__ bias,
                    const int* __restrict__ didx, const float* __restrict__ dwt,
                    void* __restrict__ outv, int vshift_in, int vshift_out, int nbl)
{
    constexpr int R    = 3*P;
    constexpr int KTOT = 12*C_IN;
    constexpr int KT   = KTOT/64;
    constexpr int WTM  = R/WGM;
    constexpr int WTN  = BN/WGN;
    constexpr int NMT  = WTM/16;
    constexpr int NNT  = WTN/16;
    constexpr int C4   = BN/4;
    static_assert(WTM % 16 == 0 && WTN % 16 == 0, "tile");
    static_assert(R <= 256 && (P*C4) % 256 == 0, "loops");

    __shared__ unsigned short gidx[R*12];
    __shared__ _Float16 E[R*(BN+4)];

    const int tid  = threadIdx.x;
    const int wave = tid >> 6;
    const int lane = tid & 63;
    const int quad = lane >> 4;
    const int l16  = lane & 15;
    const int wm   = wave / WGN;
    const int wn   = wave % WGN;
    const int pu0  = block_pu0(blockIdx.x, P, vshift_out, nbl);
    const int n0   = blockIdx.y * BN;
    const int vmask_out = (1 << vshift_out) - 1;
    const int base_in = (pu0 >> vshift_out) << vshift_in;

    // ---- one-time: gidx[r][s] = spiral[didx[u][kp]][s] (u16) ----
    if (tid < R) {
        int ul = tid / 3;
        int kp = tid - ul*3;
        int u  = (pu0 + ul) & vmask_out;
        int v  = didx[u*3 + kp];
        const int* svp = spiral + v*12;
        #pragma unroll
        for (int j = 0; j < 12; ++j) gidx[tid*12 + j] = (unsigned short)svp[j];
    }
    __syncthreads();

    f32x4 acc[NMT][NNT];
    #pragma unroll
    for (int i = 0; i < NMT; ++i)
        #pragma unroll
        for (int j = 0; j < NNT; ++j) acc[i][j] = (f32x4){0.f, 0.f, 0.f, 0.f};

    const _Float16* xb = x + (size_t)base_in * C_IN;

    for (int t = 0; t < KT; ++t) {
        #pragma unroll
        for (int kt = 0; kt < 2; ++kt) {
            const int k0 = t*64 + kt*32;
            const int s  = k0 / C_IN;                    // vertex slot 0..11
            const int c  = (k0 & (C_IN-1)) + quad*8;     // channel offset
            f16x8 af[NMT];
            #pragma unroll
            for (int i = 0; i < NMT; ++i) {
                int m_local = wm*WTM + i*16 + l16;
                int g = gidx[m_local*12 + s];
                af[i] = *(const f16x8*)&xb[(size_t)g*C_IN + c];
            }
            const _Float16* wsrc = Wp + ((size_t)((blockIdx.y*KT + t)*8 + kt*4 + quad))*BN*8;
            f16x8 bf[NNT];
            #pragma unroll
            for (int j = 0; j < NNT; ++j) {
                int n_local = wn*WTN + j*16 + l16;
                bf[j] = *(const f16x8*)&wsrc[n_local*8];
            }
            #pragma unroll
            for (int i = 0; i < NMT; ++i)
                #pragma unroll
                for (int j = 0; j < NNT; ++j)
                    acc[i][j] = __builtin_amdgcn_mfma_f32_16x16x32_f16(
                        af[i], bf[j], acc[i][j], 0, 0, 0);
        }
    }

    // ---- epilogue: bias+ELU rows into LDS (fp16), then 3-row weighted combine ----
    float bv[NNT];
    #pragma unroll
    for (int j = 0; j < NNT; ++j)
        bv[j] = bias[n0 + wn*WTN + j*16 + l16];

    #pragma unroll
    for (int i = 0; i < NMT; ++i) {
        int row_base = wm*WTM + i*16 + quad*4;
        #pragma unroll
        for (int j = 0; j < NNT; ++j) {
            int col = wn*WTN + j*16 + l16;
            #pragma unroll
            for (int r = 0; r < 4; ++r)
                E[(size_t)(row_base + r)*(BN+4) + col] =
                    (_Float16)elu_f(acc[i][j][r] + bv[j]);
        }
    }
    __syncthreads();

    #pragma unroll
    for (int e = tid; e < P*C4; e += 256) {
        int ul = e / C4;
        int c4 = e - ul*C4;
        int pu = pu0 + ul;
        int u  = pu & vmask_out;
        const float* w = dwt + u*3;
        f16x4 a0 = *(const f16x4*)&E[(size_t)(ul*3 + 0)*(BN+4) + c4*4];
        f16x4 a1 = *(const f16x4*)&E[(size_t)(ul*3 + 1)*(BN+4) + c4*4];
        f16x4 a2 = *(const f16x4*)&E[(size_t)(ul*3 + 2)*(BN+4) + c4*4];
        float ox = w[0]*(float)a0[0] + w[1]*(float)a1[0] + w[2]*(float)a2[0];
        float oy = w[0]*(float)a0[1] + w[1]*(float)a1[1] + w[2]*(float)a2[1];
        float oz = w[0]*(float)a0[2] + w[1]*(float)a1[2] + w[2]*(float)a2[2];
        float ow = w[0]*(float)a0[3] + w[1]*(float)a1[3] + w[2]*(float)a2[3];
        if (OUT_HALF) {
            f16x4 h; h[0]=(_Float16)ox; h[1]=(_Float16)oy; h[2]=(_Float16)oz; h[3]=(_Float16)ow;
            *(f16x4*)&((_Float16*)outv)[(size_t)pu*C_OUT + n0 + c4*4] = h;
        } else {
            float4 o; o.x=ox; o.y=oy; o.z=oz; o.w=ow;
            *(float4*)&((float*)outv)[(size_t)pu*C_OUT + n0 + c4*4] = o;
        }
    }
}

// ---------------- fused conv0+pool0, direct-to-register (fp16 padded x, K=48->64) ----------------
// P=64, R=192, BN=32. A-chunk = two gathered 8 B vertex rows; kt=1 quads 2-3 feed zeros.
__global__ __launch_bounds__(256)
void conv0_pool_mfma(const _Float16* __restrict__ xh4, const int* __restrict__ spiral,
                     const _Float16* __restrict__ Wp, const float* __restrict__ bias,
                     const int* __restrict__ didx, const float* __restrict__ dwt,
                     _Float16* __restrict__ out, int nbl)
{
    constexpr int P = 64, R = 192, BN = 32;
    constexpr int NMT = 3, NNT = 2;          // 4 waves x (48 rows, 32 cols)
    constexpr int C4 = BN/4;

    __shared__ unsigned short gidx[R*12];
    __shared__ _Float16 E[R*(BN+4)];

    const int tid  = threadIdx.x;
    const int wave = tid >> 6;
    const int lane = tid & 63;
    const int quad = lane >> 4;
    const int l16  = lane & 15;
    const int pu0  = block_pu0(blockIdx.x, P, 13, nbl);
    const int base = (pu0 >> 13) << 15;

    if (tid < R) {
        int ul = tid / 3;
        int kp = tid - ul*3;
        int u  = (pu0 + ul) & 8191;
        int v  = didx[u*3 + kp];
        const int* svp = spiral + v*12;
        #pragma unroll
        for (int j = 0; j < 12; ++j) gidx[tid*12 + j] = (unsigned short)svp[j];
    }
    __syncthreads();

    f32x4 acc[NMT][NNT];
    #pragma unroll
    for (int i = 0; i < NMT; ++i)
        #pragma unroll
        for (int j = 0; j < NNT; ++j) acc[i][j] = (f32x4){0.f, 0.f, 0.f, 0.f};

    const _Float16* xb = xh4 + (size_t)base * 4;

    #pragma unroll
    for (int kt = 0; kt < 2; ++kt) {
        const int kc = kt*4 + quad;          // chunk 0..7; 6,7 are zero-pad
        f16x8 af[NMT];
        #pragma unroll
        for (int i = 0; i < NMT; ++i) {
            f16x8 h = (f16x8){0,0,0,0,0,0,0,0};
            if (kc < 6) {
                int m_local = wave*48 + i*16 + l16;
                int g0 = gidx[m_local*12 + kc*2];
                int g1 = gidx[m_local*12 + kc*2 + 1];
                f16x4 a = *(const f16x4*)&xb[(size_t)g0*4];
                f16x4 b = *(const f16x4*)&xb[(size_t)g1*4];
                h[0]=a[0]; h[1]=a[1]; h[2]=a[2]; h[3]=a[3];
                h[4]=b[0]; h[5]=b[1]; h[6]=b[2]; h[7]=b[3];
            }
            af[i] = h;
        }
        const _Float16* wsrc = Wp + (size_t)kc*BN*8;
        f16x8 bf[NNT];
        #pragma unroll
        for (int j = 0; j < NNT; ++j) {
            int n_local = j*16 + l16;
            bf[j] = *(const f16x8*)&wsrc[n_local*8];
        }
        #pragma unroll
        for (int i = 0; i < NMT; ++i)
            #pragma unroll
            for (int j = 0; j < NNT; ++j)
                acc[i][j] = __builtin_amdgcn_mfma_f32_16x16x32_f16(
                    af[i], bf[j], acc[i][j], 0, 0, 0);
    }

    float bv[NNT];
    #pragma unroll
    for (int j = 0; j < NNT; ++j) bv[j] = bias[j*16 + l16];

    #pragma unroll
    for (int i = 0; i < NMT; ++i) {
        int row_base = wave*48 + i*16 + quad*4;
        #pragma unroll
        for (int j = 0; j < NNT; ++j) {
            int col = j*16 + l16;
            #pragma unroll
            for (int r = 0; r < 4; ++r)
                E[(size_t)(row_base + r)*(BN+4) + col] =
                    (_Float16)elu_f(acc[i][j][r] + bv[j]);
        }
    }
    __syncthreads();

    #pragma unroll
    for (int e = tid; e < P*C4; e += 256) {
        int ul = e / C4;
        int c4 = e - ul*C4;
        int pu = pu0 + ul;
        int u  = pu & 8191;
        const float* w = dwt + u*3;
        f16x4 a0 = *(const f16x4*)&E[(size_t)(ul*3 + 0)*(BN+4) + c4*4];
        f16x4 a1 = *(const f16x4*)&E[(size_t)(ul*3 + 1)*(BN+4) + c4*4];
        f16x4 a2 = *(const f16x4*)&E[(size_t)(ul*3 + 2)*(BN+4) + c4*4];
        f16x4 h;
        h[0] = (_Float16)(w[0]*(float)a0[0] + w[1]*(float)a1[0] + w[2]*(float)a2[0]);
        h[1] = (_Float16)(w[0]*(float)a0[1] + w[1]*(float)a1[1] + w[2]*(float)a2[1]);
        h[2] = (_Float16)(w[0]*(float)a0[2] + w[1]*(float)a1[2] + w[2]*(float)a2[2]);
        h[3] = (_Float16)(w[0]*(float)a0[3] + w[1]*(float)a1[3] + w[2]*(float)a2[3]);
        *(f16x4*)&out[(size_t)pu*BN + c4*4] = h;
    }
}

// ---------------- FC1: atomic-free split-K ----------------
__global__ __launch_bounds__(256)
void fc1_partial(const float* __restrict__ xflat, const float* __restrict__ Wl1,
                 float* __restrict__ partial)
{
    __shared__ float sb[8704];
    const int tid = threadIdx.x;
    const int n4 = tid & 31;
    const int kq = (tid >> 5) & 3;
    const int mh = tid >> 7;
    const int nt = blockIdx.x;
    const int ks = blockIdx.y;
    const int kbase = ks * 256;

    for (int e = tid; e < 2048; e += 256) {
        int m = e >> 6, k4 = e & 63;
        *(float4*)&sb[m*256 + k4*4] = *(const float4*)&xflat[(size_t)m*32768 + kbase + k4*4];
    }
    __syncthreads();

    float acc[16][4];
    #pragma unroll
    for (int m = 0; m < 16; ++m)
        #pragma unroll
        for (int c = 0; c < 4; ++c) acc[m][c] = 0.0f;

    const float* Wb = Wl1 + (size_t)(kbase + kq*64)*512 + nt*128 + n4*4;
    #pragma unroll 2
    for (int i = 0; i < 64; i += 4) {
        float4 w0 = *(const float4*)(Wb + (size_t)(i+0)*512);
        float4 w1 = *(const float4*)(Wb + (size_t)(i+1)*512);
        float4 w2 = *(const float4*)(Wb + (size_t)(i+2)*512);
        float4 w3 = *(const float4*)(Wb + (size_t)(i+3)*512);
        #pragma unroll
        for (int m = 0; m < 16; ++m) {
            float4 xv = *(const float4*)&sb[(mh*16 + m)*256 + kq*64 + i];
            acc[m][0] += xv.x*w0.x + xv.y*w1.x + xv.z*w2.x + xv.w*w3.x;
            acc[m][1] += xv.x*w0.y + xv.y*w1.y + xv.z*w2.y + xv.w*w3.y;
            acc[m][2] += xv.x*w0.z + xv.y*w1.z + xv.z*w2.z + xv.w*w3.z;
            acc[m][3] += xv.x*w0.w + xv.y*w1.w + xv.z*w2.w + xv.w*w3.w;
        }
    }
    __syncthreads();

    int slot = (mh*2 + (kq >> 1))*32 + n4;
    if (kq & 1) {
        #pragma unroll
        for (int m = 0; m < 16; ++m)
            *(float4*)&sb[slot*68 + m*4] = *(float4*)&acc[m][0];
    }
    __syncthreads();
    if (!(kq & 1)) {
        #pragma unroll
        for (int m = 0; m < 16; ++m) {
            float4 v = *(const float4*)&sb[slot*68 + m*4];
            acc[m][0] += v.x; acc[m][1] += v.y; acc[m][2] += v.z; acc[m][3] += v.w;
        }
    }
    __syncthreads();
    int slot2 = mh*32 + n4;
    if (kq == 2) {
        #pragma unroll
        for (int m = 0; m < 16; ++m)
            *(float4*)&sb[slot2*68 + m*4] = *(float4*)&acc[m][0];
    }
    __syncthreads();
    if (kq == 0) {
        float* pb = partial + ((size_t)(ks*4 + nt)*32 + mh*16)*128 + n4*4;
        #pragma unroll
        for (int m = 0; m < 16; ++m) {
            float4 v = *(const float4*)&sb[slot2*68 + m*4];
            float4 o;
            o.x = acc[m][0] + v.x; o.y = acc[m][1] + v.y;
            o.z = acc[m][2] + v.z; o.w = acc[m][3] + v.w;
            *(float4*)(pb + (size_t)m*128) = o;
        }
    }
}

__global__ __launch_bounds__(256)
void fc1_reduce(const float* __restrict__ partial, const float* __restrict__ bl1,
                float* __restrict__ hout)
{
    int i = blockIdx.x * 256 + threadIdx.x;
    int m = i >> 9, n = i & 511;
    int nt = n >> 7, nl = n & 127;
    const float* p = partial + ((size_t)nt*32 + m)*128 + nl;
    float s = 0.0f;
    #pragma unroll 8
    for (int ks = 0; ks < 128; ++ks)
        s += p[(size_t)ks*4*4096];
    hout[i] = elu_f(s + bl1[n]);
}

__global__ __launch_bounds__(64)
void fc2_kernel(const float* __restrict__ h, const float* __restrict__ Wl2,
                const float* __restrict__ bl2, float* __restrict__ y)
{
    int m = blockIdx.x;
    int n = threadIdx.x;
    float s = bl2[n];
    for (int k = 0; k < 512; ++k)
        s += h[(size_t)m*512 + k] * Wl2[(size_t)k*64 + n];
    y[(size_t)m*64 + n] = s;
}

extern "C" void kernel_launch(void* const* d_in, const int* in_sizes, int n_in,
                              void* d_out, int out_size, void* d_ws, size_t ws_size,
                              hipStream_t stream)
{
    (void)in_sizes; (void)n_in; (void)out_size;

    const float* x0 = (const float*)d_in[0];
    const int*   sp[4]; const int* didx[4]; const float* dwp[4];
    const float* Wp[4]; const float* bp[4];
    for (int i = 0; i < 4; ++i) {
        sp[i]   = (const int*)  d_in[1 + i*5 + 0];
        didx[i] = (const int*)  d_in[1 + i*5 + 1];
        dwp[i]  = (const float*)d_in[1 + i*5 + 2];
        Wp[i]   = (const float*)d_in[1 + i*5 + 3];
        bp[i]   = (const float*)d_in[1 + i*5 + 4];
    }
    const float* Wl1 = (const float*)d_in[21];
    const float* bl1 = (const float*)d_in[22];
    const float* Wl2 = (const float*)d_in[23];
    const float* bl2 = (const float*)d_in[24];
    float* out = (float*)d_out;

    char* wsb = (char*)d_ws;
    float* persist   = (float*)wsb;                      // 4 MB (32,128,256) fp32
    float* partial   = (float*)(wsb + 4194304);          // 8.4 MB: 512 x 4096 floats
    _Float16* w0h    = (_Float16*)(wsb + 12582912);      //   2,048 halfs
    _Float16* w1h    = w0h + 2048;                       //  24,576 halfs
    _Float16* w2h    = w1h + 24576;                      //  98,304 halfs
    _Float16* w3h    = w2h + 98304;                      // 393,216 halfs
    char* bufs       = wsb + 13619200;

    // per-batch-unit: xh4 256K + pooled0 512K + pooled1 256K + pooled2 128K
    int Bc = 32;
    while (Bc > 1 && (size_t)13619200 + (size_t)Bc*1179648ULL > ws_size)
        Bc >>= 1;
    _Float16* xh4     = (_Float16*)bufs;
    _Float16* pooled0 = xh4 + (size_t)Bc*131072ULL;
    _Float16* pooled1 = pooled0 + (size_t)Bc*262144ULL;
    _Float16* pooled2 = pooled1 + (size_t)Bc*131072ULL;

    int nbl = (Bc == 32) ? 2 : (Bc == 16) ? 1 : (Bc == 8) ? 0 : -1;

    prep_w0<<<8, 256, 0, stream>>>(Wp[0], w0h);
    prep_w< 384,  64,  64><<<( 24576 + 255)/256, 256, 0, stream>>>(Wp[1], w1h);
    prep_w< 768, 128, 128><<<( 98304 + 255)/256, 256, 0, stream>>>(Wp[2], w2h);
    prep_w<1536, 256,  64><<<(393216 + 255)/256, 256, 0, stream>>>(Wp[3], w3h);

    for (int b0 = 0; b0 < 32; b0 += Bc) {
        const float* xin = x0 + (size_t)b0*32768*3;

        prep_x<<<(Bc*32768 + 255)/256, 256, 0, stream>>>(xin, xh4, Bc*32768);

        // L0: conv(4->32, K=48 pad 64) + pool -> fp16 (Bc, 8192, 32)
        conv0_pool_mfma<<<Bc*8192/64, 256, 0, stream>>>(
            xh4, sp[0], w0h, bp[0], didx[0], dwp[0], pooled0, nbl);

        // L1: conv(32->64, K=384) + pool -> fp16 (Bc, 2048, 64)
        conv_pool_mfma<32,64,64,64,4,1,true><<<Bc*2048/64, 256, 0, stream>>>(
            pooled0, sp[1], w1h, bp[1], didx[1], dwp[1], pooled1, 13, 11, nbl);

        // L2: conv(64->128, K=768) + pool -> fp16 (Bc, 512, 128)
        conv_pool_mfma<64,128,32,128,2,2,true><<<Bc*512/32, 256, 0, stream>>>(
            pooled1, sp[2], w2h, bp[2], didx[2], dwp[2], pooled2, 11, 9, nbl);

        // L3: conv(128->256, K=1536) + pool -> fp32 persist (Bc, 128, 256)
        conv_pool_mfma<128,256,32,64,2,2,false><<<dim3(Bc*128/32, 4), 256, 0, stream>>>(
            pooled2, sp[3], w3h, bp[3], didx[3], dwp[3],
            persist + (size_t)b0*32768, 9, 7, nbl);
    }

    // FC1: (32,32768)@(32768,512), split-K partials then reduce+bias+ELU
    fc1_partial<<<dim3(4, 128), 256, 0, stream>>>(persist, Wl1, partial);
    fc1_reduce<<<64, 256, 0, stream>>>(partial, bl1, out);

    // FC2: (32,512)@(512,64) + bias -> d_out[16384:18432]
    fc2_kernel<<<32, 64, 0, stream>>>(out, Wl2, bl2, out + 16384);
}